// Round 15
// baseline (197.483 us; speedup 1.0000x reference)
//
#include <hip/hip_runtime.h>
#include <hip/hip_bf16.h>
#include <cstdint>
#include <cstddef>

#define S_LEN 2048
#define N_HEADS 16
#define HD 64
#define EMB 1024
#define N_BATCH 2
#define N_BH (N_BATCH * N_HEADS)

typedef __attribute__((ext_vector_type(4))) float f32x4;
typedef __attribute__((ext_vector_type(8))) short short8;      // 16B raw container
typedef __attribute__((ext_vector_type(8))) _Float16 half8;    // f16 MFMA frag
typedef __attribute__((ext_vector_type(2))) unsigned uint2v;
typedef __attribute__((ext_vector_type(4))) unsigned uint4v;

__device__ __forceinline__ f32x4 mfma16h(half8 a, half8 b, f32x4 c) {
    return __builtin_amdgcn_mfma_f32_16x16x32_f16(a, b, c, 0, 0, 0);
}

__device__ __forceinline__ unsigned pkh(float a, float b) {
    return __builtin_bit_cast(unsigned, __builtin_amdgcn_cvt_pkrtz(a, b));
}

#if __has_builtin(__builtin_amdgcn_exp2f)
__device__ __forceinline__ float fast_exp2(float x) { return __builtin_amdgcn_exp2f(x); }
#else
__device__ __forceinline__ float fast_exp2(float x) { return exp2f(x); }
#endif

// HBM -> LDS direct (16B/lane, wave-uniform LDS base + lane*16).
__device__ __forceinline__ void gl2lds16(const short* g, short* l) {
    __builtin_amdgcn_global_load_lds(
        (const __attribute__((address_space(1))) void*)g,
        (__attribute__((address_space(3))) void*)l, 16, 0, 0);
}

// ---------------------------------------------------------------------------
// Kernel 1 (MERGED prep): blocks [0,3072) QKV projection; [3072,11264) mask
// pack; [11264,11776) Wo fp32->f16.
// proj: Q,K row-major f16 [bh][2048][64] (Q pre-scaled by log2(e)/32);
//       V transposed f16 [bh][64][2048], with the 8B-group swap (1<->2 within
//       each 16-short window) PRE-APPLIED so attn can stage V via
//       global_load_lds with a pure chunk-XOR source swizzle (rule #21).
// ---------------------------------------------------------------------------
__global__ __launch_bounds__(256) void prep_kernel(
    const float* __restrict__ q_in, const float* __restrict__ k_in,
    const float* __restrict__ v_in,
    const float* __restrict__ Wq, const float* __restrict__ Wk,
    const float* __restrict__ Wv, const float* __restrict__ Wo,
    const int* __restrict__ mask,
    short* __restrict__ Qb, short* __restrict__ Kb, short* __restrict__ Vt,
    short* __restrict__ Woh, unsigned long long* __restrict__ bits) {
    __shared__ short Al[64 * 72];
    __shared__ short Wl[64 * 72];
    __shared__ short Ol[64 * 72];
    int bx = blockIdx.x;
    int t = threadIdx.x;

    if (bx >= 3072) {
        if (bx < 11264) {
            // ---- mask pack: 1 bit/elem via ballot ----
            int wid = ((bx - 3072) * 256 + t) >> 6;
            int lane = t & 63;
            const int* src = mask + (size_t)wid * 256 + lane;
            unsigned long long w0 = __ballot(src[0] != 0);
            unsigned long long w1 = __ballot(src[64] != 0);
            unsigned long long w2 = __ballot(src[128] != 0);
            unsigned long long w3 = __ballot(src[192] != 0);
            if (lane == 0) {
                unsigned long long* dst = bits + (size_t)wid * 4;
                dst[0] = w0; dst[1] = w1; dst[2] = w2; dst[3] = w3;
            }
        } else {
            // ---- Wo fp32 -> f16 (8 floats/thread) ----
            int i = (bx - 11264) * 256 + t;
            f32x4 a = reinterpret_cast<const f32x4*>(Wo)[i * 2];
            f32x4 b = reinterpret_cast<const f32x4*>(Wo)[i * 2 + 1];
            uint4 u = { pkh(a.x, a.y), pkh(a.z, a.w), pkh(b.x, b.y), pkh(b.z, b.w) };
            reinterpret_cast<uint4*>(Woh)[i] = u;
        }
        return;
    }

    // ---- QKV projection ----
    int rt = bx & 31;           // row tile
    int bh = (bx >> 5) & 31;    // head
    int tz = bx >> 10;          // 0:Q 1:K 2:V
    const float* src = (tz == 0 ? q_in : tz == 1 ? k_in : v_in)
                       + (size_t)bh * S_LEN * HD + (size_t)rt * 64 * HD;
    const float* W = (tz == 0 ? Wq : tz == 1 ? Wk : Wv);

#pragma unroll
    for (int r = 0; r < 4; r++) {
        int f4 = t + 256 * r;
        int row = f4 >> 4;
        int c4 = (f4 & 15) * 4;
        f32x4 a = reinterpret_cast<const f32x4*>(src)[f4];
        uint2 ua = { pkh(a.x, a.y), pkh(a.z, a.w) };
        *reinterpret_cast<uint2*>(&Al[row * 72 + c4]) = ua;
        f32x4 w = reinterpret_cast<const f32x4*>(W)[f4];
        uint2 uw = { pkh(w.x, w.y), pkh(w.z, w.w) };
        *reinterpret_cast<uint2*>(&Wl[row * 72 + c4]) = uw;
    }
    __syncthreads();

    int wave = t >> 6, lane = t & 63, quad = lane >> 4, col = lane & 15;
    half8 a0 = *reinterpret_cast<const half8*>(&Al[(wave * 16 + col) * 72 + quad * 8]);
    half8 a1 = *reinterpret_cast<const half8*>(&Al[(wave * 16 + col) * 72 + 32 + quad * 8]);

    const float C1 = 0.04508422002777448f;  // log2(e)/32
    float scl = (tz == 0) ? C1 : 1.0f;

    f32x4 acc[4];
#pragma unroll
    for (int jt = 0; jt < 4; jt++) {
        half8 b0 = *reinterpret_cast<const half8*>(&Wl[(jt * 16 + col) * 72 + quad * 8]);
        half8 b1 = *reinterpret_cast<const half8*>(&Wl[(jt * 16 + col) * 72 + 32 + quad * 8]);
        f32x4 c = {0.f, 0.f, 0.f, 0.f};
        c = mfma16h(a0, b0, c);
        c = mfma16h(a1, b1, c);
        acc[jt] = c;
    }
    __syncthreads();

    if (tz < 2) {
#pragma unroll
        for (int jt = 0; jt < 4; jt++)
#pragma unroll
            for (int i = 0; i < 4; i++)
                Ol[(wave * 16 + quad * 4 + i) * 72 + jt * 16 + col] =
                    __builtin_bit_cast(short, (_Float16)(acc[jt][i] * scl));
        __syncthreads();
        short* dst = (tz == 0 ? Qb : Kb) + (size_t)bh * S_LEN * HD + (size_t)rt * 64 * HD;
        int row = t >> 2, ck = (t & 3) * 16;
        short8 o0 = *reinterpret_cast<const short8*>(&Ol[row * 72 + ck]);
        short8 o1 = *reinterpret_cast<const short8*>(&Ol[row * 72 + ck + 8]);
        *reinterpret_cast<short8*>(&dst[row * 64 + ck]) = o0;
        *reinterpret_cast<short8*>(&dst[row * 64 + ck + 8]) = o1;
    } else {
#pragma unroll
        for (int jt = 0; jt < 4; jt++)
#pragma unroll
            for (int i = 0; i < 4; i++)
                Ol[(jt * 16 + col) * 72 + wave * 16 + quad * 4 + i] =
                    __builtin_bit_cast(short, (_Float16)acc[jt][i]);
        __syncthreads();
        short* dst = Vt + (size_t)bh * HD * S_LEN + rt * 64;
        int d = t >> 2, ck = (t & 3) * 16;
        short8 o0 = *reinterpret_cast<const short8*>(&Ol[d * 72 + ck]);
        short8 o1 = *reinterpret_cast<const short8*>(&Ol[d * 72 + ck + 8]);
        // Pre-apply the 8B-group 1<->2 swap within this 16-short window:
        // positions {0,1,2,3} get groups {g0,g2,g1,g3}.
        uint4v u0 = __builtin_bit_cast(uint4v, o0);
        uint4v u1 = __builtin_bit_cast(uint4v, o1);
        short8 n0 = __builtin_bit_cast(short8, (uint4v){u0.x, u0.y, u1.x, u1.y});
        short8 n1 = __builtin_bit_cast(short8, (uint4v){u0.z, u0.w, u1.z, u1.w});
        *reinterpret_cast<short8*>(&dst[(size_t)d * S_LEN + ck]) = n0;
        *reinterpret_cast<short8*>(&dst[(size_t)d * S_LEN + ck + 8]) = n1;
    }
}

// ---------------------------------------------------------------------------
// Kernel 2 (R16 config, best measured total 190.87us): flash attention, f16,
// BQ=128, 512 thr = 8 waves = 4 q-groups x 2 kv-parities.  R6 compute body;
// K/V staged via global_load_lds with pre-swizzled per-lane sources; cross-
// iteration double-buffer, ONE barrier/iter.  T1 XCD remap: all 16 qt-blocks
// of one head co-locate on an XCD (FETCH 70->14.4MB); costs ~+1.5us locally
// but pays back in final via warm-L2 Xb reads (best total).
// ---------------------------------------------------------------------------
__global__ __launch_bounds__(512, 4) void attn_kernel(
    const short* __restrict__ Qb, const short* __restrict__ Kb,
    const short* __restrict__ Vt, const unsigned long long* __restrict__ mbits,
    short* __restrict__ Xb) {
    // T1 remap: w = qt + 16*bh; xcd = w&7 constant per head group.
    int w = blockIdx.x + 16 * blockIdx.y;  // 0..511
    int kk = w >> 3;
    int bh = (w & 7) * 4 + (kk & 3);       // 0..31
    int qt = kk >> 2;                      // 0..15
    int b = bh >> 4;
    int t = threadIdx.x, wave = t >> 6, lane = t & 63, quad = lane >> 4, col = lane & 15;
    int qg = wave & 3;    // q-group: 32 rows each
    int par = wave >> 2;  // kv parity: tiles 2s+par

    // smem (shorts, 64KB): K [0,16384) = par0{ph0,ph1}, par1{ph0,ph1}
    // (4096 shorts each phase); V [16384,32768) same structure.
    // Epilogue reuse: Obuf f32 [0,16384) | Ps [16384,25600) | Lbuf [25600,25856).
    __shared__ short smem[32768];

    const short* Qh = Qb + (size_t)bh * S_LEN * HD;
    const short* Kh = Kb + (size_t)bh * S_LEN * HD;
    const short* Vh = Vt + (size_t)bh * HD * S_LEN;
    int q0 = qt * 128 + qg * 32;

    half8 qf00 = *reinterpret_cast<const half8*>(&Qh[(size_t)(q0 + col) * HD + quad * 8]);
    half8 qf01 = *reinterpret_cast<const half8*>(&Qh[(size_t)(q0 + col) * HD + 32 + quad * 8]);
    half8 qf10 = *reinterpret_cast<const half8*>(&Qh[(size_t)(q0 + 16 + col) * HD + quad * 8]);
    half8 qf11 = *reinterpret_cast<const half8*>(&Qh[(size_t)(q0 + 16 + col) * HD + 32 + quad * 8]);

    const unsigned long long* mrow0 = mbits + (size_t)(b * S_LEN + q0 + col) * 32;
    const unsigned long long* mrow1 = mbits + (size_t)(b * S_LEN + q0 + 16 + col) * 32;

    // ---- gl_lds staging: wave w stages 1KB chunk w of each of the 4 tiles.
    // Per-lane source swizzle: row = 8w + (lane>>3); chunk = (lane&7) ^ (row&7).
    int lrow = lane >> 3;
    int lsw = (lane & 7) ^ lrow;          // row&7 == lrow (rows 8w-aligned)
    int grow = wave * 8 + lrow;
    const short* kp0 = Kh + grow * 64 + lsw * 8;               // +4096/kv-tile
    const short* vp0 = Vh + (size_t)grow * S_LEN + lsw * 8;    // +64/kv-tile
    short* kl0 = smem + wave * 512;            // K par0 chunk base (ph0)
    short* kl1 = smem + 8192 + wave * 512;     // K par1
    short* vl0 = smem + 16384 + wave * 512;    // V par0
    short* vl1 = smem + 24576 + wave * 512;    // V par1

    // initial: tiles 0 (par0) / 1 (par1) into phase 0
    gl2lds16(kp0, kl0);
    gl2lds16(kp0 + 4096, kl1);
    gl2lds16(vp0, vl0);
    gl2lds16(vp0 + 64, vl1);

    unsigned bs[4];
#pragma unroll
    for (int i = 0; i < 4; i++) bs[i] = 1u << (quad * 4 + i);
    half8 ones = { (_Float16)1.f, (_Float16)1.f, (_Float16)1.f, (_Float16)1.f,
                   (_Float16)1.f, (_Float16)1.f, (_Float16)1.f, (_Float16)1.f };

    int sw = quad ^ (col & 7);
    unsigned long long mw0 = mrow0[par];
    unsigned long long mw1 = mrow1[par];

    f32x4 o[4][2];
    f32x4 l0 = {0.f, 0.f, 0.f, 0.f}, l1 = {0.f, 0.f, 0.f, 0.f};
#pragma unroll
    for (int dt = 0; dt < 4; dt++) {
        o[dt][0] = (f32x4){0.f, 0.f, 0.f, 0.f};
        o[dt][1] = (f32x4){0.f, 0.f, 0.f, 0.f};
    }
    __syncthreads();   // drains initial gl_lds (implicit vmcnt(0))

    for (int s = 0; s < 16; s++) {
        int rd = (s & 1) * 4096;   // read phase offset (shorts)
        int wr = 4096 - rd;        // write phase offset
        unsigned long long mn0, mn1;
        if (s < 15) {
            const short* ka = kp0 + (2 * s + 2) * 4096;
            const short* va = vp0 + (2 * s + 2) * 64;
            gl2lds16(ka, kl0 + wr);
            gl2lds16(ka + 4096, kl1 + wr);
            gl2lds16(va, vl0 + wr);
            gl2lds16(va + 64, vl1 + wr);
            mn0 = mrow0[2 * s + 2 + par];
            mn1 = mrow1[2 * s + 2 + par];
        }
        const short* Kp = smem + par * 8192 + rd;
        const short* Vp = smem + 16384 + par * 8192 + rd;
        // ---- S^T = K·Q^T + lane-local softmax numerator, kept in registers ----
        unsigned wA[4][2], wB[4][2];
#pragma unroll
        for (int mt = 0; mt < 4; mt++) {
            const short* kbase = &Kp[(mt * 16 + col) * 64];
            half8 ka0 = *reinterpret_cast<const half8*>(&kbase[sw * 8]);
            half8 ka1 = *reinterpret_cast<const half8*>(&kbase[(sw ^ 4) * 8]);
            f32x4 c0 = {0.f, 0.f, 0.f, 0.f};
            f32x4 c1 = {0.f, 0.f, 0.f, 0.f};
            c0 = mfma16h(ka0, qf00, c0);
            c0 = mfma16h(ka1, qf01, c0);
            c1 = mfma16h(ka0, qf10, c1);
            c1 = mfma16h(ka1, qf11, c1);
            unsigned g0 = (unsigned)(mw0 >> (mt * 16));
            unsigned g1 = (unsigned)(mw1 >> (mt * 16));
            float p00 = fast_exp2((g0 & bs[0]) ? c0[0] : -200.0f);
            float p01 = fast_exp2((g0 & bs[1]) ? c0[1] : -200.0f);
            float p02 = fast_exp2((g0 & bs[2]) ? c0[2] : -200.0f);
            float p03 = fast_exp2((g0 & bs[3]) ? c0[3] : -200.0f);
            wA[mt][0] = pkh(p00, p01);
            wA[mt][1] = pkh(p02, p03);
            float p10 = fast_exp2((g1 & bs[0]) ? c1[0] : -200.0f);
            float p11 = fast_exp2((g1 & bs[1]) ? c1[1] : -200.0f);
            float p12 = fast_exp2((g1 & bs[2]) ? c1[2] : -200.0f);
            float p13 = fast_exp2((g1 & bs[3]) ? c1[3] : -200.0f);
            wB[mt][0] = pkh(p10, p11);
            wB[mt][1] = pkh(p12, p13);
        }
        // ---- O^T += V^T · P^T, P fragment built in-register via permlane ----
#pragma unroll
        for (int c = 0; c < 2; c++) {
            auto ra0 = __builtin_amdgcn_permlane32_swap(wA[2 * c][0], wA[2 * c + 1][0], false, false);
            auto ra1 = __builtin_amdgcn_permlane32_swap(wA[2 * c][1], wA[2 * c + 1][1], false, false);
            auto rb0 = __builtin_amdgcn_permlane32_swap(wB[2 * c][0], wB[2 * c + 1][0], false, false);
            auto rb1 = __builtin_amdgcn_permlane32_swap(wB[2 * c][1], wB[2 * c + 1][1], false, false);
            half8 pb0 = __builtin_bit_cast(half8, (uint4v){ra0[0], ra1[0], ra0[1], ra1[1]});
            half8 pb1 = __builtin_bit_cast(half8, (uint4v){rb0[0], rb1[0], rb0[1], rb1[1]});
            l0 = mfma16h(ones, pb0, l0);
            l1 = mfma16h(ones, pb1, l1);
#pragma unroll
            for (int dt = 0; dt < 4; dt++) {
                half8 va = *reinterpret_cast<const half8*>(
                    &Vp[(dt * 16 + col) * 64 + (((c * 4 + quad) ^ (col & 7)) * 8)]);
                o[dt][0] = mfma16h(va, pb0, o[dt][0]);
                o[dt][1] = mfma16h(va, pb1, o[dt][1]);
            }
        }
        if (s < 15) {
            mw0 = mn0;
            mw1 = mn1;
        }
        __syncthreads();   // one barrier/iter; implicit vmcnt(0) lands gl_lds
    }

    // ---- epilogue: combine parity partials, normalize, repack, store ----
    float* Obuf = (float*)smem;                   // [4][2048] f32 = K region
    short* Ps = smem + 16384;                     // V region: 4 x 32*72 shorts
    float* Lbuf = (float*)(smem + 25600);         // [4][32] f32
    if (par == 1) {
        float* ob = Obuf + qg * 2048 + lane * 32;
#pragma unroll
        for (int dt = 0; dt < 4; dt++) {
            *reinterpret_cast<f32x4*>(&ob[((dt * 2 + 0) ^ (lane & 7)) * 4]) = o[dt][0];
            *reinterpret_cast<f32x4*>(&ob[((dt * 2 + 1) ^ (lane & 7)) * 4]) = o[dt][1];
        }
        if (quad == 0) {
            Lbuf[qg * 32 + col] = l0[0];
            Lbuf[qg * 32 + 16 + col] = l1[0];
        }
    }
    __syncthreads();
    if (par == 0) {
        short* Pw = Ps + qg * (32 * 72);
        float* ob = Obuf + qg * 2048 + lane * 32;
        float inv0 = 1.0f / (l0[0] + Lbuf[qg * 32 + col]);
        float inv1 = 1.0f / (l1[0] + Lbuf[qg * 32 + 16 + col]);
#pragma unroll
        for (int dt = 0; dt < 4; dt++) {
            f32x4 a0 = *reinterpret_cast<const f32x4*>(&ob[((dt * 2 + 0) ^ (lane & 7)) * 4]);
            f32x4 a1 = *reinterpret_cast<const f32x4*>(&ob[((dt * 2 + 1) ^ (lane & 7)) * 4]);
            float v00 = (o[dt][0][0] + a0.x) * inv0, v01 = (o[dt][0][1] + a0.y) * inv0;
            float v02 = (o[dt][0][2] + a0.z) * inv0, v03 = (o[dt][0][3] + a0.w) * inv0;
            float v10 = (o[dt][1][0] + a1.x) * inv1, v11 = (o[dt][1][1] + a1.y) * inv1;
            float v12 = (o[dt][1][2] + a1.z) * inv1, v13 = (o[dt][1][3] + a1.w) * inv1;
            uint2 dw0 = { pkh(v00, v01), pkh(v02, v03) };
            uint2 dw1 = { pkh(v10, v11), pkh(v12, v13) };
            *reinterpret_cast<uint2*>(&Pw[col * 72 + dt * 16 + quad * 4]) = dw0;
            *reinterpret_cast<uint2*>(&Pw[(16 + col) * 72 + dt * 16 + quad * 4]) = dw1;
        }
        int rr = lane >> 2, ckk = (lane & 3) * 16;
        short* Xrow = Xb + (size_t)bh * S_LEN * HD + (size_t)(q0 + rr) * HD;
        short8 x0 = *reinterpret_cast<const short8*>(&Pw[rr * 72 + ckk]);
        short8 x1 = *reinterpret_cast<const short8*>(&Pw[rr * 72 + ckk + 8]);
        *reinterpret_cast<short8*>(&Xrow[ckk]) = x0;
        *reinterpret_cast<short8*>(&Xrow[ckk + 8]) = x1;
        short* Xrow2 = Xrow + 16 * HD;
        short8 y0 = *reinterpret_cast<const short8*>(&Pw[(16 + rr) * 72 + ckk]);
        short8 y1 = *reinterpret_cast<const short8*>(&Pw[(16 + rr) * 72 + ckk + 8]);
        *reinterpret_cast<short8*>(&Xrow2[ckk]) = y0;
        *reinterpret_cast<short8*>(&Xrow2[ckk + 8]) = y1;
    }
}

// ---------------------------------------------------------------------------
// Kernel 3 (R15 + T1, KEPT): out = X @ Wo^T + bo, 128(M)x64(N) tile,
// 256 threads, gl_lds staging, single barrier/K-step.  XCD remap co-locates
// the 16 same-mb blocks (sharing a 256KB X panel).
// ---------------------------------------------------------------------------
__global__ __launch_bounds__(256, 4) void final_kernel(
    const short* __restrict__ Xb, const short* __restrict__ Woh,
    const float* __restrict__ bo, float* __restrict__ out) {
    int w = blockIdx.x + 16 * blockIdx.y;  // 0..511
    int kk = w >> 3;
    int mb = (w & 7) * 4 + (kk & 3);       // 0..31 (128-row panel)
    int nb = kk >> 2;                      // 0..15 (64-col panel)
    int t = threadIdx.x, wave = t >> 6, lane = t & 63, quad = lane >> 4, col = lane & 15;
    __shared__ short smem[32768];   // 64 KB

    int m0 = mb * 128, n0 = nb * 64;

    // ---- gl_lds staging: lane row/chunk swizzle (rule #21) ----
    int lrow = lane >> 3;
    int lsw = (lane & 7) ^ lrow;    // row&7 == lrow (rows 8-aligned per wave)
    const short* xg = Xb + (size_t)(m0 + wave * 8 + lrow) * EMB + lsw * 8;
    const short* wg = Woh + (size_t)(n0 + wave * 8 + lrow) * EMB + lsw * 8;
    short* xl = smem + wave * 512;            // X seg {w,w+4,w+8,w+12}: +j*2048
    short* wl = smem + 16384 + wave * 512;    // W seg {w,w+4}: +j*2048

    // initial stage into phase 0 (K-step 0)
    gl2lds16(xg, xl);
    gl2lds16(xg + 32 * EMB, xl + 2048);
    gl2lds16(xg + 64 * EMB, xl + 4096);
    gl2lds16(xg + 96 * EMB, xl + 6144);
    gl2lds16(wg, wl);
    gl2lds16(wg + 32 * EMB, wl + 2048);

    int sw = quad ^ (col & 7);
    f32x4 acc[2][4];
#pragma unroll
    for (int mf = 0; mf < 2; mf++)
#pragma unroll
        for (int nf = 0; nf < 4; nf++) acc[mf][nf] = (f32x4){0.f, 0.f, 0.f, 0.f};
    __syncthreads();   // drains initial gl_lds

    for (int s = 0; s < 16; s++) {
        int rd = (s & 1) << 13;    // 0 or 8192 (shorts)
        int wr = 8192 - rd;
        if (s < 15) {
            const short* xs = xg + (s + 1) * 64;
            const short* ws2 = wg + (s + 1) * 64;
            gl2lds16(xs, xl + wr);
            gl2lds16(xs + 32 * EMB, xl + wr + 2048);
            gl2lds16(xs + 64 * EMB, xl + wr + 4096);
            gl2lds16(xs + 96 * EMB, xl + wr + 6144);
            gl2lds16(ws2, wl + wr);
            gl2lds16(ws2 + 32 * EMB, wl + wr + 2048);
        }
        const short* Xp = smem + rd;
        const short* Wp = smem + 16384 + rd;
        const short* ar0 = &Xp[(wave * 32 + col) * 64];
        const short* ar1 = &Xp[(wave * 32 + 16 + col) * 64];
        half8 a00 = *reinterpret_cast<const half8*>(&ar0[sw * 8]);
        half8 a01 = *reinterpret_cast<const half8*>(&ar0[(sw ^ 4) * 8]);
        half8 a10 = *reinterpret_cast<const half8*>(&ar1[sw * 8]);
        half8 a11 = *reinterpret_cast<const half8*>(&ar1[(sw ^ 4) * 8]);
#pragma unroll
        for (int nf = 0; nf < 4; nf++) {
            const short* br = &Wp[(nf * 16 + col) * 64];
            half8 b0 = *reinterpret_cast<const half8*>(&br[sw * 8]);
            half8 b1 = *reinterpret_cast<const half8*>(&br[(sw ^ 4) * 8]);
            acc[0][nf] = mfma16h(a00, b0, acc[0][nf]);
            acc[0][nf] = mfma16h(a01, b1, acc[0][nf]);
            acc[1][nf] = mfma16h(a10, b0, acc[1][nf]);
            acc[1][nf] = mfma16h(a11, b1, acc[1][nf]);
        }
        __syncthreads();   // one barrier/step; implicit vmcnt(0) lands gl_lds
    }

    // ---- epilogue: direct global stores, bias in-register ----
    float bb[4];
#pragma unroll
    for (int nf = 0; nf < 4; nf++) bb[nf] = bo[n0 + nf * 16 + col];
#pragma unroll
    for (int mf = 0; mf < 2; mf++)
#pragma unroll
        for (int i = 0; i < 4; i++) {
            int row = m0 + wave * 32 + mf * 16 + quad * 4 + i;
            float* orow = out + (size_t)row * EMB + n0;
#pragma unroll
            for (int nf = 0; nf < 4; nf++)
                orow[nf * 16 + col] = acc[mf][nf][i] + bb[nf];
        }
}

// ---------------------------------------------------------------------------
extern "C" void kernel_launch(void* const* d_in, const int* in_sizes, int n_in,
                              void* d_out, int out_size, void* d_ws, size_t ws_size,
                              hipStream_t stream) {
    const float* value = (const float*)d_in[0];
    const float* key_  = (const float*)d_in[1];
    const float* query = (const float*)d_in[2];
    const int*   mask  = (const int*)d_in[3];
    const float* Wq = (const float*)d_in[4];
    const float* Wk = (const float*)d_in[5];
    const float* Wv = (const float*)d_in[6];
    const float* Wo = (const float*)d_in[7];
    const float* bo = (const float*)d_in[8];
    float* out = (float*)d_out;

    char* ws = (char*)d_ws;
    short* Qb  = (short*)(ws);
    short* Kb  = (short*)(ws + (size_t)8  * 1048576);
    short* Vt  = (short*)(ws + (size_t)16 * 1048576);
    short* Xb  = (short*)(ws + (size_t)24 * 1048576);
    short* Woh = (short*)(ws + (size_t)32 * 1048576);
    unsigned long long* mbits =
        (unsigned long long*)(ws + (size_t)34 * 1048576);

    prep_kernel<<<dim3(3072 + 8192 + 512), dim3(256), 0, stream>>>(
        query, key_, value, Wq, Wk, Wv, Wo, mask, Qb, Kb, Vt, Woh, mbits);
    attn_kernel<<<dim3(S_LEN / 128, N_BH), dim3(512), 0, stream>>>(Qb, Kb, Vt, mbits, Xb);
    final_kernel<<<dim3(EMB / 64, (N_BATCH * S_LEN) / 128), dim3(256), 0, stream>>>(
        Xb, Woh, bo, out);
}

// Round 16
// 188.952 us; speedup vs baseline: 1.0451x; 1.0451x over previous
//
#include <hip/hip_runtime.h>
#include <hip/hip_bf16.h>
#include <cstdint>
#include <cstddef>

#define S_LEN 2048
#define N_HEADS 16
#define HD 64
#define EMB 1024
#define N_BATCH 2
#define N_BH (N_BATCH * N_HEADS)

typedef __attribute__((ext_vector_type(4))) float f32x4;
typedef __attribute__((ext_vector_type(8))) short short8;      // 16B raw container
typedef __attribute__((ext_vector_type(8))) _Float16 half8;    // f16 MFMA frag
typedef __attribute__((ext_vector_type(2))) unsigned uint2v;
typedef __attribute__((ext_vector_type(4))) unsigned uint4v;

__device__ __forceinline__ f32x4 mfma16h(half8 a, half8 b, f32x4 c) {
    return __builtin_amdgcn_mfma_f32_16x16x32_f16(a, b, c, 0, 0, 0);
}

__device__ __forceinline__ unsigned pkh(float a, float b) {
    return __builtin_bit_cast(unsigned, __builtin_amdgcn_cvt_pkrtz(a, b));
}

#if __has_builtin(__builtin_amdgcn_exp2f)
__device__ __forceinline__ float fast_exp2(float x) { return __builtin_amdgcn_exp2f(x); }
#else
__device__ __forceinline__ float fast_exp2(float x) { return exp2f(x); }
#endif

// HBM -> LDS direct (16B/lane, wave-uniform LDS base + lane*16).
__device__ __forceinline__ void gl2lds16(const short* g, short* l) {
    __builtin_amdgcn_global_load_lds(
        (const __attribute__((address_space(1))) void*)g,
        (__attribute__((address_space(3))) void*)l, 16, 0, 0);
}

// ---------------------------------------------------------------------------
// Kernel 1 (MERGED prep): blocks [0,3072) QKV projection; [3072,11264) mask
// pack; [11264,11776) Wo fp32->f16.
// proj: Q,K row-major f16 [bh][2048][64] (Q pre-scaled by log2(e)/32);
//       V transposed f16 [bh][64][2048], with the 8B-group swap (1<->2 within
//       each 16-short window) PRE-APPLIED so attn can stage V via
//       global_load_lds with a pure chunk-XOR source swizzle (rule #21).
// ---------------------------------------------------------------------------
__global__ __launch_bounds__(256) void prep_kernel(
    const float* __restrict__ q_in, const float* __restrict__ k_in,
    const float* __restrict__ v_in,
    const float* __restrict__ Wq, const float* __restrict__ Wk,
    const float* __restrict__ Wv, const float* __restrict__ Wo,
    const int* __restrict__ mask,
    short* __restrict__ Qb, short* __restrict__ Kb, short* __restrict__ Vt,
    short* __restrict__ Woh, unsigned long long* __restrict__ bits) {
    __shared__ short Al[64 * 72];
    __shared__ short Wl[64 * 72];
    __shared__ short Ol[64 * 72];
    int bx = blockIdx.x;
    int t = threadIdx.x;

    if (bx >= 3072) {
        if (bx < 11264) {
            // ---- mask pack: 1 bit/elem via ballot ----
            int wid = ((bx - 3072) * 256 + t) >> 6;
            int lane = t & 63;
            const int* src = mask + (size_t)wid * 256 + lane;
            unsigned long long w0 = __ballot(src[0] != 0);
            unsigned long long w1 = __ballot(src[64] != 0);
            unsigned long long w2 = __ballot(src[128] != 0);
            unsigned long long w3 = __ballot(src[192] != 0);
            if (lane == 0) {
                unsigned long long* dst = bits + (size_t)wid * 4;
                dst[0] = w0; dst[1] = w1; dst[2] = w2; dst[3] = w3;
            }
        } else {
            // ---- Wo fp32 -> f16 (8 floats/thread) ----
            int i = (bx - 11264) * 256 + t;
            f32x4 a = reinterpret_cast<const f32x4*>(Wo)[i * 2];
            f32x4 b = reinterpret_cast<const f32x4*>(Wo)[i * 2 + 1];
            uint4 u = { pkh(a.x, a.y), pkh(a.z, a.w), pkh(b.x, b.y), pkh(b.z, b.w) };
            reinterpret_cast<uint4*>(Woh)[i] = u;
        }
        return;
    }

    // ---- QKV projection ----
    int rt = bx & 31;           // row tile
    int bh = (bx >> 5) & 31;    // head
    int tz = bx >> 10;          // 0:Q 1:K 2:V
    const float* src = (tz == 0 ? q_in : tz == 1 ? k_in : v_in)
                       + (size_t)bh * S_LEN * HD + (size_t)rt * 64 * HD;
    const float* W = (tz == 0 ? Wq : tz == 1 ? Wk : Wv);

#pragma unroll
    for (int r = 0; r < 4; r++) {
        int f4 = t + 256 * r;
        int row = f4 >> 4;
        int c4 = (f4 & 15) * 4;
        f32x4 a = reinterpret_cast<const f32x4*>(src)[f4];
        uint2 ua = { pkh(a.x, a.y), pkh(a.z, a.w) };
        *reinterpret_cast<uint2*>(&Al[row * 72 + c4]) = ua;
        f32x4 w = reinterpret_cast<const f32x4*>(W)[f4];
        uint2 uw = { pkh(w.x, w.y), pkh(w.z, w.w) };
        *reinterpret_cast<uint2*>(&Wl[row * 72 + c4]) = uw;
    }
    __syncthreads();

    int wave = t >> 6, lane = t & 63, quad = lane >> 4, col = lane & 15;
    half8 a0 = *reinterpret_cast<const half8*>(&Al[(wave * 16 + col) * 72 + quad * 8]);
    half8 a1 = *reinterpret_cast<const half8*>(&Al[(wave * 16 + col) * 72 + 32 + quad * 8]);

    const float C1 = 0.04508422002777448f;  // log2(e)/32
    float scl = (tz == 0) ? C1 : 1.0f;

    f32x4 acc[4];
#pragma unroll
    for (int jt = 0; jt < 4; jt++) {
        half8 b0 = *reinterpret_cast<const half8*>(&Wl[(jt * 16 + col) * 72 + quad * 8]);
        half8 b1 = *reinterpret_cast<const half8*>(&Wl[(jt * 16 + col) * 72 + 32 + quad * 8]);
        f32x4 c = {0.f, 0.f, 0.f, 0.f};
        c = mfma16h(a0, b0, c);
        c = mfma16h(a1, b1, c);
        acc[jt] = c;
    }
    __syncthreads();

    if (tz < 2) {
#pragma unroll
        for (int jt = 0; jt < 4; jt++)
#pragma unroll
            for (int i = 0; i < 4; i++)
                Ol[(wave * 16 + quad * 4 + i) * 72 + jt * 16 + col] =
                    __builtin_bit_cast(short, (_Float16)(acc[jt][i] * scl));
        __syncthreads();
        short* dst = (tz == 0 ? Qb : Kb) + (size_t)bh * S_LEN * HD + (size_t)rt * 64 * HD;
        int row = t >> 2, ck = (t & 3) * 16;
        short8 o0 = *reinterpret_cast<const short8*>(&Ol[row * 72 + ck]);
        short8 o1 = *reinterpret_cast<const short8*>(&Ol[row * 72 + ck + 8]);
        *reinterpret_cast<short8*>(&dst[row * 64 + ck]) = o0;
        *reinterpret_cast<short8*>(&dst[row * 64 + ck + 8]) = o1;
    } else {
#pragma unroll
        for (int jt = 0; jt < 4; jt++)
#pragma unroll
            for (int i = 0; i < 4; i++)
                Ol[(jt * 16 + col) * 72 + wave * 16 + quad * 4 + i] =
                    __builtin_bit_cast(short, (_Float16)acc[jt][i]);
        __syncthreads();
        short* dst = Vt + (size_t)bh * HD * S_LEN + rt * 64;
        int d = t >> 2, ck = (t & 3) * 16;
        short8 o0 = *reinterpret_cast<const short8*>(&Ol[d * 72 + ck]);
        short8 o1 = *reinterpret_cast<const short8*>(&Ol[d * 72 + ck + 8]);
        // Pre-apply the 8B-group 1<->2 swap within this 16-short window:
        // positions {0,1,2,3} get groups {g0,g2,g1,g3}.
        uint4v u0 = __builtin_bit_cast(uint4v, o0);
        uint4v u1 = __builtin_bit_cast(uint4v, o1);
        short8 n0 = __builtin_bit_cast(short8, (uint4v){u0.x, u0.y, u1.x, u1.y});
        short8 n1 = __builtin_bit_cast(short8, (uint4v){u0.z, u0.w, u1.z, u1.w});
        *reinterpret_cast<short8*>(&dst[(size_t)d * S_LEN + ck]) = n0;
        *reinterpret_cast<short8*>(&dst[(size_t)d * S_LEN + ck + 8]) = n1;
    }
}

// ---------------------------------------------------------------------------
// Kernel 2 (FINAL, identity mapping — best measured attn 55.0-56.3us):
// flash attention, f16, BQ=128, 512 thr = 8 waves = 4 q-groups x 2 kv-
// parities.  R6 compute body; K/V staged via global_load_lds with pre-
// swizzled per-lane sources; cross-iteration double-buffer, ONE barrier/iter.
// WRITE_SIZE=8.2MB (no spill).  T1 XCD remap measured SLOWER here (57.2,
// 58.5 vs 55.0, 55.0, 56.0) — kernel is latency-bound at 5-18% HBM BW, and
// co-located lockstep blocks contend on one L2.  Identity mapping kept.
// Register-ceiling guard: 5 structural variants (dbuf/occupancy/setprio)
// all spilled; do not add live state or scheduling perturbations.
// ---------------------------------------------------------------------------
__global__ __launch_bounds__(512, 4) void attn_kernel(
    const short* __restrict__ Qb, const short* __restrict__ Kb,
    const short* __restrict__ Vt, const unsigned long long* __restrict__ mbits,
    short* __restrict__ Xb) {
    int qt = blockIdx.x;  // 0..15
    int bh = blockIdx.y;  // 0..31
    int b = bh >> 4;
    int t = threadIdx.x, wave = t >> 6, lane = t & 63, quad = lane >> 4, col = lane & 15;
    int qg = wave & 3;    // q-group: 32 rows each
    int par = wave >> 2;  // kv parity: tiles 2s+par

    // smem (shorts, 64KB): K [0,16384) = par0{ph0,ph1}, par1{ph0,ph1}
    // (4096 shorts each phase); V [16384,32768) same structure.
    // Epilogue reuse: Obuf f32 [0,16384) | Ps [16384,25600) | Lbuf [25600,25856).
    __shared__ short smem[32768];

    const short* Qh = Qb + (size_t)bh * S_LEN * HD;
    const short* Kh = Kb + (size_t)bh * S_LEN * HD;
    const short* Vh = Vt + (size_t)bh * HD * S_LEN;
    int q0 = qt * 128 + qg * 32;

    half8 qf00 = *reinterpret_cast<const half8*>(&Qh[(size_t)(q0 + col) * HD + quad * 8]);
    half8 qf01 = *reinterpret_cast<const half8*>(&Qh[(size_t)(q0 + col) * HD + 32 + quad * 8]);
    half8 qf10 = *reinterpret_cast<const half8*>(&Qh[(size_t)(q0 + 16 + col) * HD + quad * 8]);
    half8 qf11 = *reinterpret_cast<const half8*>(&Qh[(size_t)(q0 + 16 + col) * HD + 32 + quad * 8]);

    const unsigned long long* mrow0 = mbits + (size_t)(b * S_LEN + q0 + col) * 32;
    const unsigned long long* mrow1 = mbits + (size_t)(b * S_LEN + q0 + 16 + col) * 32;

    // ---- gl_lds staging: wave w stages 1KB chunk w of each of the 4 tiles.
    // Per-lane source swizzle: row = 8w + (lane>>3); chunk = (lane&7) ^ (row&7).
    int lrow = lane >> 3;
    int lsw = (lane & 7) ^ lrow;          // row&7 == lrow (rows 8w-aligned)
    int grow = wave * 8 + lrow;
    const short* kp0 = Kh + grow * 64 + lsw * 8;               // +4096/kv-tile
    const short* vp0 = Vh + (size_t)grow * S_LEN + lsw * 8;    // +64/kv-tile
    short* kl0 = smem + wave * 512;            // K par0 chunk base (ph0)
    short* kl1 = smem + 8192 + wave * 512;     // K par1
    short* vl0 = smem + 16384 + wave * 512;    // V par0
    short* vl1 = smem + 24576 + wave * 512;    // V par1

    // initial: tiles 0 (par0) / 1 (par1) into phase 0
    gl2lds16(kp0, kl0);
    gl2lds16(kp0 + 4096, kl1);
    gl2lds16(vp0, vl0);
    gl2lds16(vp0 + 64, vl1);

    unsigned bs[4];
#pragma unroll
    for (int i = 0; i < 4; i++) bs[i] = 1u << (quad * 4 + i);
    half8 ones = { (_Float16)1.f, (_Float16)1.f, (_Float16)1.f, (_Float16)1.f,
                   (_Float16)1.f, (_Float16)1.f, (_Float16)1.f, (_Float16)1.f };

    int sw = quad ^ (col & 7);
    unsigned long long mw0 = mrow0[par];
    unsigned long long mw1 = mrow1[par];

    f32x4 o[4][2];
    f32x4 l0 = {0.f, 0.f, 0.f, 0.f}, l1 = {0.f, 0.f, 0.f, 0.f};
#pragma unroll
    for (int dt = 0; dt < 4; dt++) {
        o[dt][0] = (f32x4){0.f, 0.f, 0.f, 0.f};
        o[dt][1] = (f32x4){0.f, 0.f, 0.f, 0.f};
    }
    __syncthreads();   // drains initial gl_lds (implicit vmcnt(0))

    for (int s = 0; s < 16; s++) {
        int rd = (s & 1) * 4096;   // read phase offset (shorts)
        int wr = 4096 - rd;        // write phase offset
        unsigned long long mn0, mn1;
        if (s < 15) {
            const short* ka = kp0 + (2 * s + 2) * 4096;
            const short* va = vp0 + (2 * s + 2) * 64;
            gl2lds16(ka, kl0 + wr);
            gl2lds16(ka + 4096, kl1 + wr);
            gl2lds16(va, vl0 + wr);
            gl2lds16(va + 64, vl1 + wr);
            mn0 = mrow0[2 * s + 2 + par];
            mn1 = mrow1[2 * s + 2 + par];
        }
        const short* Kp = smem + par * 8192 + rd;
        const short* Vp = smem + 16384 + par * 8192 + rd;
        // ---- S^T = K·Q^T + lane-local softmax numerator, kept in registers ----
        unsigned wA[4][2], wB[4][2];
#pragma unroll
        for (int mt = 0; mt < 4; mt++) {
            const short* kbase = &Kp[(mt * 16 + col) * 64];
            half8 ka0 = *reinterpret_cast<const half8*>(&kbase[sw * 8]);
            half8 ka1 = *reinterpret_cast<const half8*>(&kbase[(sw ^ 4) * 8]);
            f32x4 c0 = {0.f, 0.f, 0.f, 0.f};
            f32x4 c1 = {0.f, 0.f, 0.f, 0.f};
            c0 = mfma16h(ka0, qf00, c0);
            c0 = mfma16h(ka1, qf01, c0);
            c1 = mfma16h(ka0, qf10, c1);
            c1 = mfma16h(ka1, qf11, c1);
            unsigned g0 = (unsigned)(mw0 >> (mt * 16));
            unsigned g1 = (unsigned)(mw1 >> (mt * 16));
            float p00 = fast_exp2((g0 & bs[0]) ? c0[0] : -200.0f);
            float p01 = fast_exp2((g0 & bs[1]) ? c0[1] : -200.0f);
            float p02 = fast_exp2((g0 & bs[2]) ? c0[2] : -200.0f);
            float p03 = fast_exp2((g0 & bs[3]) ? c0[3] : -200.0f);
            wA[mt][0] = pkh(p00, p01);
            wA[mt][1] = pkh(p02, p03);
            float p10 = fast_exp2((g1 & bs[0]) ? c1[0] : -200.0f);
            float p11 = fast_exp2((g1 & bs[1]) ? c1[1] : -200.0f);
            float p12 = fast_exp2((g1 & bs[2]) ? c1[2] : -200.0f);
            float p13 = fast_exp2((g1 & bs[3]) ? c1[3] : -200.0f);
            wB[mt][0] = pkh(p10, p11);
            wB[mt][1] = pkh(p12, p13);
        }
        // ---- O^T += V^T · P^T, P fragment built in-register via permlane ----
#pragma unroll
        for (int c = 0; c < 2; c++) {
            auto ra0 = __builtin_amdgcn_permlane32_swap(wA[2 * c][0], wA[2 * c + 1][0], false, false);
            auto ra1 = __builtin_amdgcn_permlane32_swap(wA[2 * c][1], wA[2 * c + 1][1], false, false);
            auto rb0 = __builtin_amdgcn_permlane32_swap(wB[2 * c][0], wB[2 * c + 1][0], false, false);
            auto rb1 = __builtin_amdgcn_permlane32_swap(wB[2 * c][1], wB[2 * c + 1][1], false, false);
            half8 pb0 = __builtin_bit_cast(half8, (uint4v){ra0[0], ra1[0], ra0[1], ra1[1]});
            half8 pb1 = __builtin_bit_cast(half8, (uint4v){rb0[0], rb1[0], rb0[1], rb1[1]});
            l0 = mfma16h(ones, pb0, l0);
            l1 = mfma16h(ones, pb1, l1);
#pragma unroll
            for (int dt = 0; dt < 4; dt++) {
                half8 va = *reinterpret_cast<const half8*>(
                    &Vp[(dt * 16 + col) * 64 + (((c * 4 + quad) ^ (col & 7)) * 8)]);
                o[dt][0] = mfma16h(va, pb0, o[dt][0]);
                o[dt][1] = mfma16h(va, pb1, o[dt][1]);
            }
        }
        if (s < 15) {
            mw0 = mn0;
            mw1 = mn1;
        }
        __syncthreads();   // one barrier/iter; implicit vmcnt(0) lands gl_lds
    }

    // ---- epilogue: combine parity partials, normalize, repack, store ----
    float* Obuf = (float*)smem;                   // [4][2048] f32 = K region
    short* Ps = smem + 16384;                     // V region: 4 x 32*72 shorts
    float* Lbuf = (float*)(smem + 25600);         // [4][32] f32
    if (par == 1) {
        float* ob = Obuf + qg * 2048 + lane * 32;
#pragma unroll
        for (int dt = 0; dt < 4; dt++) {
            *reinterpret_cast<f32x4*>(&ob[((dt * 2 + 0) ^ (lane & 7)) * 4]) = o[dt][0];
            *reinterpret_cast<f32x4*>(&ob[((dt * 2 + 1) ^ (lane & 7)) * 4]) = o[dt][1];
        }
        if (quad == 0) {
            Lbuf[qg * 32 + col] = l0[0];
            Lbuf[qg * 32 + 16 + col] = l1[0];
        }
    }
    __syncthreads();
    if (par == 0) {
        short* Pw = Ps + qg * (32 * 72);
        float* ob = Obuf + qg * 2048 + lane * 32;
        float inv0 = 1.0f / (l0[0] + Lbuf[qg * 32 + col]);
        float inv1 = 1.0f / (l1[0] + Lbuf[qg * 32 + 16 + col]);
#pragma unroll
        for (int dt = 0; dt < 4; dt++) {
            f32x4 a0 = *reinterpret_cast<const f32x4*>(&ob[((dt * 2 + 0) ^ (lane & 7)) * 4]);
            f32x4 a1 = *reinterpret_cast<const f32x4*>(&ob[((dt * 2 + 1) ^ (lane & 7)) * 4]);
            float v00 = (o[dt][0][0] + a0.x) * inv0, v01 = (o[dt][0][1] + a0.y) * inv0;
            float v02 = (o[dt][0][2] + a0.z) * inv0, v03 = (o[dt][0][3] + a0.w) * inv0;
            float v10 = (o[dt][1][0] + a1.x) * inv1, v11 = (o[dt][1][1] + a1.y) * inv1;
            float v12 = (o[dt][1][2] + a1.z) * inv1, v13 = (o[dt][1][3] + a1.w) * inv1;
            uint2 dw0 = { pkh(v00, v01), pkh(v02, v03) };
            uint2 dw1 = { pkh(v10, v11), pkh(v12, v13) };
            *reinterpret_cast<uint2*>(&Pw[col * 72 + dt * 16 + quad * 4]) = dw0;
            *reinterpret_cast<uint2*>(&Pw[(16 + col) * 72 + dt * 16 + quad * 4]) = dw1;
        }
        int rr = lane >> 2, ckk = (lane & 3) * 16;
        short* Xrow = Xb + (size_t)bh * S_LEN * HD + (size_t)(q0 + rr) * HD;
        short8 x0 = *reinterpret_cast<const short8*>(&Pw[rr * 72 + ckk]);
        short8 x1 = *reinterpret_cast<const short8*>(&Pw[rr * 72 + ckk + 8]);
        *reinterpret_cast<short8*>(&Xrow[ckk]) = x0;
        *reinterpret_cast<short8*>(&Xrow[ckk + 8]) = x1;
        short* Xrow2 = Xrow + 16 * HD;
        short8 y0 = *reinterpret_cast<const short8*>(&Pw[(16 + rr) * 72 + ckk]);
        short8 y1 = *reinterpret_cast<const short8*>(&Pw[(16 + rr) * 72 + ckk + 8]);
        *reinterpret_cast<short8*>(&Xrow2[ckk]) = y0;
        *reinterpret_cast<short8*>(&Xrow2[ckk + 8]) = y1;
    }
}

// ---------------------------------------------------------------------------
// Kernel 3 (FINAL: R15 + T1): out = X @ Wo^T + bo, 128(M)x64(N) tile,
// 256 threads, gl_lds staging, single barrier/K-step.  XCD remap co-locates
// the 16 same-mb blocks (sharing a 256KB X panel); delivered ~-5us when
// introduced (R15->R16) and is kept.
// ---------------------------------------------------------------------------
__global__ __launch_bounds__(256, 4) void final_kernel(
    const short* __restrict__ Xb, const short* __restrict__ Woh,
    const float* __restrict__ bo, float* __restrict__ out) {
    int w = blockIdx.x + 16 * blockIdx.y;  // 0..511
    int kk = w >> 3;
    int mb = (w & 7) * 4 + (kk & 3);       // 0..31 (128-row panel)
    int nb = kk >> 2;                      // 0..15 (64-col panel)
    int t = threadIdx.x, wave = t >> 6, lane = t & 63, quad = lane >> 4, col = lane & 15;
    __shared__ short smem[32768];   // 64 KB

    int m0 = mb * 128, n0 = nb * 64;

    // ---- gl_lds staging: lane row/chunk swizzle (rule #21) ----
    int lrow = lane >> 3;
    int lsw = (lane & 7) ^ lrow;    // row&7 == lrow (rows 8-aligned per wave)
    const short* xg = Xb + (size_t)(m0 + wave * 8 + lrow) * EMB + lsw * 8;
    const short* wg = Woh + (size_t)(n0 + wave * 8 + lrow) * EMB + lsw * 8;
    short* xl = smem + wave * 512;            // X seg {w,w+4,w+8,w+12}: +j*2048
    short* wl = smem + 16384 + wave * 512;    // W seg {w,w+4}: +j*2048

    // initial stage into phase 0 (K-step 0)
    gl2lds16(xg, xl);
    gl2lds16(xg + 32 * EMB, xl + 2048);
    gl2lds16(xg + 64 * EMB, xl + 4096);
    gl2lds16(xg + 96 * EMB, xl + 6144);
    gl2lds16(wg, wl);
    gl2lds16(wg + 32 * EMB, wl + 2048);

    int sw = quad ^ (col & 7);
    f32x4 acc[2][4];
#pragma unroll
    for (int mf = 0; mf < 2; mf++)
#pragma unroll
        for (int nf = 0; nf < 4; nf++) acc[mf][nf] = (f32x4){0.f, 0.f, 0.f, 0.f};
    __syncthreads();   // drains initial gl_lds

    for (int s = 0; s < 16; s++) {
        int rd = (s & 1) << 13;    // 0 or 8192 (shorts)
        int wr = 8192 - rd;
        if (s < 15) {
            const short* xs = xg + (s + 1) * 64;
            const short* ws2 = wg + (s + 1) * 64;
            gl2lds16(xs, xl + wr);
            gl2lds16(xs + 32 * EMB, xl + wr + 2048);
            gl2lds16(xs + 64 * EMB, xl + wr + 4096);
            gl2lds16(xs + 96 * EMB, xl + wr + 6144);
            gl2lds16(ws2, wl + wr);
            gl2lds16(ws2 + 32 * EMB, wl + wr + 2048);
        }
        const short* Xp = smem + rd;
        const short* Wp = smem + 16384 + rd;
        const short* ar0 = &Xp[(wave * 32 + col) * 64];
        const short* ar1 = &Xp[(wave * 32 + 16 + col) * 64];
        half8 a00 = *reinterpret_cast<const half8*>(&ar0[sw * 8]);
        half8 a01 = *reinterpret_cast<const half8*>(&ar0[(sw ^ 4) * 8]);
        half8 a10 = *reinterpret_cast<const half8*>(&ar1[sw * 8]);
        half8 a11 = *reinterpret_cast<const half8*>(&ar1[(sw ^ 4) * 8]);
#pragma unroll
        for (int nf = 0; nf < 4; nf++) {
            const short* br = &Wp[(nf * 16 + col) * 64];
            half8 b0 = *reinterpret_cast<const half8*>(&br[sw * 8]);
            half8 b1 = *reinterpret_cast<const half8*>(&br[(sw ^ 4) * 8]);
            acc[0][nf] = mfma16h(a00, b0, acc[0][nf]);
            acc[0][nf] = mfma16h(a01, b1, acc[0][nf]);
            acc[1][nf] = mfma16h(a10, b0, acc[1][nf]);
            acc[1][nf] = mfma16h(a11, b1, acc[1][nf]);
        }
        __syncthreads();   // one barrier/step; implicit vmcnt(0) lands gl_lds
    }

    // ---- epilogue: direct global stores, bias in-register ----
    float bb[4];
#pragma unroll
    for (int nf = 0; nf < 4; nf++) bb[nf] = bo[n0 + nf * 16 + col];
#pragma unroll
    for (int mf = 0; mf < 2; mf++)
#pragma unroll
        for (int i = 0; i < 4; i++) {
            int row = m0 + wave * 32 + mf * 16 + quad * 4 + i;
            float* orow = out + (size_t)row * EMB + n0;
#pragma unroll
            for (int nf = 0; nf < 4; nf++)
                orow[nf * 16 + col] = acc[mf][nf][i] + bb[nf];
        }
}

// ---------------------------------------------------------------------------
extern "C" void kernel_launch(void* const* d_in, const int* in_sizes, int n_in,
                              void* d_out, int out_size, void* d_ws, size_t ws_size,
                              hipStream_t stream) {
    const float* value = (const float*)d_in[0];
    const float* key_  = (const float*)d_in[1];
    const float* query = (const float*)d_in[2];
    const int*   mask  = (const int*)d_in[3];
    const float* Wq = (const float*)d_in[4];
    const float* Wk = (const float*)d_in[5];
    const float* Wv = (const float*)d_in[6];
    const float* Wo = (const float*)d_in[7];
    const float* bo = (const float*)d_in[8];
    float* out = (float*)d_out;

    char* ws = (char*)d_ws;
    short* Qb  = (short*)(ws);
    short* Kb  = (short*)(ws + (size_t)8  * 1048576);
    short* Vt  = (short*)(ws + (size_t)16 * 1048576);
    short* Xb  = (short*)(ws + (size_t)24 * 1048576);
    short* Woh = (short*)(ws + (size_t)32 * 1048576);
    unsigned long long* mbits =
        (unsigned long long*)(ws + (size_t)34 * 1048576);

    prep_kernel<<<dim3(3072 + 8192 + 512), dim3(256), 0, stream>>>(
        query, key_, value, Wq, Wk, Wv, Wo, mask, Qb, Kb, Vt, Woh, mbits);
    attn_kernel<<<dim3(S_LEN / 128, N_BH), dim3(512), 0, stream>>>(Qb, Kb, Vt, mbits, Xb);
    final_kernel<<<dim3(EMB / 64, (N_BATCH * S_LEN) / 128), dim3(256), 0, stream>>>(
        Xb, Woh, bo, out);
}